// Round 17
// baseline (286.060 us; speedup 1.0000x reference)
//
#include <hip/hip_runtime.h>
#include <cstdint>

#define D_MODEL 1024
#define D_INNER 2048
#define NHEADS 32
#define HEADDIM 64
#define D_STATE 128
#define CONV_DIM 2304
#define D_IN_PROJ 4384
#define SEQ 4096
#define NROWS 8192          // BATCH*SEQ
#define NPROJ_PAD 4480      // 35*128
#define TCH 128             // SSD chunk length
#define NCHUNK 32           // SEQ / TCH
#define CR 8                // conv rows per thread

typedef float f32x4 __attribute__((ext_vector_type(4)));
typedef __bf16 bf16x8 __attribute__((ext_vector_type(8)));
typedef unsigned short u16;

__device__ __forceinline__ u16 f2bf(float f) {
  uint32_t u = __builtin_bit_cast(uint32_t, f);
  u += 0x7FFFu + ((u >> 16) & 1u);
  return (u16)(u >> 16);
}
__device__ __forceinline__ float bf2f(u16 h) {
  return __builtin_bit_cast(float, (uint32_t)h << 16);
}
// decay exponent is mathematically <= 0; clamp kills rounding/edge inf risk
__device__ __forceinline__ float dexp(float a) { return expf(fminf(0.f, a)); }
// transpose-LDS t-swizzle (verified conflict-free both sides, round 9)
__device__ __forceinline__ int sw(int v) { return (((v & 7) ^ ((v >> 3) & 7)) << 3); }

typedef __attribute__((address_space(1))) const void gv_t;
typedef __attribute__((address_space(3))) void lv_t;
__device__ __forceinline__ void gload_lds16(const void* g, void* l) {
  __builtin_amdgcn_global_load_lds((gv_t*)g, (lv_t*)l, 16, 0, 0);
}

// ---------------------------------------------------------------- cvt f32->bf16 (+zero pad)
__global__ __launch_bounds__(256) void cvt_pad(const float* __restrict__ s,
                                               u16* __restrict__ d, int n_src, int n_dst) {
  int i = (blockIdx.x * 256 + threadIdx.x) * 4;
  int stride = gridDim.x * 256 * 4;
  for (; i < n_dst; i += stride) {
    ushort4 o;
    if (i < n_src) {
      float4 v = *(const float4*)&s[i];
      o.x = f2bf(v.x); o.y = f2bf(v.y); o.z = f2bf(v.z); o.w = f2bf(v.w);
    } else {
      o.x = o.y = o.z = o.w = 0;
    }
    *(ushort4*)&d[i] = o;
  }
}

// ---------------------------------------------------------------- cvt W2 with norm_w fold
__global__ __launch_bounds__(256) void cvt_w2s(const float* __restrict__ s,
                                               const float* __restrict__ nw,
                                               u16* __restrict__ d, int n) {
  int i = (blockIdx.x * 256 + threadIdx.x) * 4;
  int stride = gridDim.x * 256 * 4;
  for (; i < n; i += stride) {
    float4 v = *(const float4*)&s[i];
    int c = i & (D_INNER - 1);  // 4 consecutive cols, no wrap (i % 4 == 0)
    ushort4 o;
    o.x = f2bf(v.x * nw[c]);
    o.y = f2bf(v.y * nw[c + 1]);
    o.z = f2bf(v.z * nw[c + 2]);
    o.w = f2bf(v.w * nw[c + 3]);
    *(ushort4*)&d[i] = o;
  }
}

// ---------------------------------------------------------------- LayerNorm -> bf16
__global__ __launch_bounds__(256) void ln_kernel(const float* __restrict__ x,
                                                 const float* __restrict__ w,
                                                 const float* __restrict__ b,
                                                 u16* __restrict__ out) {
  int row = blockIdx.x, tid = threadIdx.x;
  const float4 v = *(const float4*)&x[(long)row * D_MODEL + tid * 4];
  float s1 = v.x + v.y + v.z + v.w;
  float s2 = v.x * v.x + v.y * v.y + v.z * v.z + v.w * v.w;
#pragma unroll
  for (int m = 32; m >= 1; m >>= 1) {
    s1 += __shfl_xor(s1, m);
    s2 += __shfl_xor(s2, m);
  }
  __shared__ float p1[4], p2[4];
  if ((tid & 63) == 0) { p1[tid >> 6] = s1; p2[tid >> 6] = s2; }
  __syncthreads();
  s1 = p1[0] + p1[1] + p1[2] + p1[3];
  s2 = p2[0] + p2[1] + p2[2] + p2[3];
  float mean = s1 * (1.f / D_MODEL);
  float var = s2 * (1.f / D_MODEL) - mean * mean;
  float rstd = rsqrtf(var + 1e-5f);
  const float4 wv = *(const float4*)&w[tid * 4];
  const float4 bv = *(const float4*)&b[tid * 4];
  ushort4 o;
  o.x = f2bf((v.x - mean) * rstd * wv.x + bv.x);
  o.y = f2bf((v.y - mean) * rstd * wv.y + bv.y);
  o.z = f2bf((v.z - mean) * rstd * wv.z + bv.z);
  o.w = f2bf((v.w - mean) * rstd * wv.w + bv.w);
  *(ushort4*)&out[(long)row * D_MODEL + tid * 4] = o;
}

// ---------------------------------------------------------------- bf16 GEMM1 C=A*B^T
// 2-D super-tiles of 8m x 5n per XCD (A 2MB + B 1.25MB fit XCD L2).
// Split-store epilogue: z bf16 / xBC bf16 / dt f32.
__global__ __launch_bounds__(256, 4) void gemm_bt(const u16* __restrict__ A,
                                                  const u16* __restrict__ B, int K,
                                                  u16* __restrict__ zb,
                                                  u16* __restrict__ xb,
                                                  float* __restrict__ dtb) {
  __shared__ __align__(16) u16 As[128 * 64];  // 16 KB
  __shared__ __align__(16) u16 Bs[128 * 64];
  const int tid = threadIdx.x;
  const int k = (blockIdx.x & 7) * 280 + (blockIdx.x >> 3);
  const int st = k / 40, inner = k % 40;
  const int m0 = ((st & 7) * 8 + (inner & 7)) * 128;
  const int n0 = ((st >> 3) * 5 + (inner >> 3)) * 128;
  const int w = tid >> 6, l = tid & 63;
  const int wm = w >> 1, wn = w & 1;

  f32x4 acc[4][4] = {};

  for (int k0 = 0; k0 < K; k0 += 64) {
#pragma unroll
    for (int i = 0; i < 4; ++i) {
      int idx = i * 256 + tid;                 // 1024 slots = 128 rows x 8 slots
      int row = idx >> 3, slot = idx & 7;
      int ks = slot ^ (row & 7);               // inverse swizzle on global source
      const u16* ga = A + (long)(m0 + row) * K + k0 + ks * 8;
      gload_lds16(ga, (char*)As + idx * 16);
      const u16* gb = B + (long)(n0 + row) * K + k0 + ks * 8;
      gload_lds16(gb, (char*)Bs + idx * 16);
    }
    __syncthreads();
    bf16x8 af[2][4], bfr[2][4];
#pragma unroll
    for (int kk = 0; kk < 2; ++kk)
#pragma unroll
      for (int f = 0; f < 4; ++f) {
        int rowa = wm * 64 + f * 16 + (l & 15);
        int ca = ((kk << 2) | (l >> 4)) ^ (rowa & 7);
        af[kk][f] = *(const bf16x8*)((const char*)As + rowa * 128 + ca * 16);
        int rowb = wn * 64 + f * 16 + (l & 15);
        int cb2 = ((kk << 2) | (l >> 4)) ^ (rowb & 7);
        bfr[kk][f] = *(const bf16x8*)((const char*)Bs + rowb * 128 + cb2 * 16);
      }
#pragma unroll
    for (int kk = 0; kk < 2; ++kk)
#pragma unroll
      for (int mf = 0; mf < 4; ++mf)
#pragma unroll
        for (int nf = 0; nf < 4; ++nf)
          acc[mf][nf] = __builtin_amdgcn_mfma_f32_16x16x32_bf16(
              af[kk][mf], bfr[kk][nf], acc[mf][nf], 0, 0, 0);
    __syncthreads();
  }
#pragma unroll
  for (int mf = 0; mf < 4; ++mf)
#pragma unroll
    for (int nf = 0; nf < 4; ++nf) {
      int col = n0 + wn * 64 + nf * 16 + (l & 15);
#pragma unroll
      for (int r = 0; r < 4; ++r) {
        int rowm = m0 + wm * 64 + mf * 16 + (l >> 4) * 4 + r;
        float v = acc[mf][nf][r];
        if (col < D_INNER)
          zb[(long)rowm * D_INNER + col] = f2bf(v);
        else if (col < D_INNER + CONV_DIM)
          xb[(long)rowm * CONV_DIM + (col - D_INNER)] = f2bf(v);
        else if (col < D_IN_PROJ)
          dtb[(long)rowm * NHEADS + (col - D_INNER - CONV_DIM)] = v;
      }
    }
}

// ---------------------------------------------------------------- bf16 GEMM2 (out-proj)
// 64x128 tile -> 1024 blocks (4/CU, double gemm-template concurrency).
// XCD map: B-panel (0.5MB) resident per 16-block group; A-slice via L3.
// Epilogue: rvec row scale (fused RMSNorm) + residual, f32 out.
__global__ __launch_bounds__(256, 4) void gemm2_kernel(const u16* __restrict__ A,
                                                       const u16* __restrict__ B,
                                                       float* __restrict__ C,
                                                       const float* __restrict__ resid,
                                                       const float* __restrict__ rvec) {
  __shared__ __align__(16) u16 As[64 * 64];    // 8 KB
  __shared__ __align__(16) u16 Bs[128 * 64];   // 16 KB
  const int tid = threadIdx.x;
  const int xcd = blockIdx.x & 7, i0 = blockIdx.x >> 3;  // i0 in [0,128)
  const int m0 = (xcd * 16 + (i0 & 15)) * 64;            // 64-row m-tile
  const int n0 = (i0 >> 4) * 128;                        // 128-col n-panel
  const int w = tid >> 6, l = tid & 63;
  const int K = D_INNER;

  f32x4 acc[4][2] = {};

  for (int k0 = 0; k0 < K; k0 += 64) {
#pragma unroll
    for (int i = 0; i < 2; ++i) {              // A: 512 slots (64 rows x 8)
      int idx = i * 256 + tid;
      int row = idx >> 3, slot = idx & 7;
      int ks = slot ^ (row & 7);
      gload_lds16(A + (long)(m0 + row) * K + k0 + ks * 8, (char*)As + idx * 16);
    }
#pragma unroll
    for (int i = 0; i < 4; ++i) {              // B: 1024 slots (128 rows x 8)
      int idx = i * 256 + tid;
      int row = idx >> 3, slot = idx & 7;
      int ks = slot ^ (row & 7);
      gload_lds16(B + (long)(n0 + row) * K + k0 + ks * 8, (char*)Bs + idx * 16);
    }
    __syncthreads();
    bf16x8 af[2][4], bfr[2][2];
#pragma unroll
    for (int kk = 0; kk < 2; ++kk) {
#pragma unroll
      for (int f = 0; f < 4; ++f) {
        int rowa = f * 16 + (l & 15);
        int ca = ((kk << 2) | (l >> 4)) ^ (rowa & 7);
        af[kk][f] = *(const bf16x8*)((const char*)As + rowa * 128 + ca * 16);
      }
#pragma unroll
      for (int f = 0; f < 2; ++f) {
        int rowb = w * 32 + f * 16 + (l & 15);
        int cb2 = ((kk << 2) | (l >> 4)) ^ (rowb & 7);
        bfr[kk][f] = *(const bf16x8*)((const char*)Bs + rowb * 128 + cb2 * 16);
      }
    }
#pragma unroll
    for (int kk = 0; kk < 2; ++kk)
#pragma unroll
      for (int mf = 0; mf < 4; ++mf)
#pragma unroll
        for (int nf = 0; nf < 2; ++nf)
          acc[mf][nf] = __builtin_amdgcn_mfma_f32_16x16x32_bf16(
              af[kk][mf], bfr[kk][nf], acc[mf][nf], 0, 0, 0);
    __syncthreads();
  }
#pragma unroll
  for (int mf = 0; mf < 4; ++mf)
#pragma unroll
    for (int nf = 0; nf < 2; ++nf) {
      int col = n0 + w * 32 + nf * 16 + (l & 15);
#pragma unroll
      for (int r = 0; r < 4; ++r) {
        int rowm = m0 + mf * 16 + (l >> 4) * 4 + r;
        long off = (long)rowm * D_MODEL + col;
        C[off] = acc[mf][nf][r] * rvec[rowm] + resid[off];
      }
    }
}

// ---------------------------------------------------------------- conv1d + SiLU
__global__ __launch_bounds__(256) void conv_silu_kernel(const u16* __restrict__ xr,
                                                        const float* __restrict__ cw,
                                                        const float* __restrict__ cb,
                                                        u16* __restrict__ xp,
                                                        u16* __restrict__ bc) {
  const int c = blockIdx.x * 256 + threadIdx.x;   // 0..2303 exact (grid.x = 9)
  const int row0 = blockIdx.y * CR;
  const int t0 = row0 & (SEQ - 1);
  const float4 wv = *(const float4*)&cw[c * 4];
  const float bias = cb[c];
  float xwin[CR + 3];
#pragma unroll
  for (int k = 0; k < CR + 3; ++k) {
    int t = t0 - 3 + k;
    xwin[k] = (t >= 0) ? bf2f(xr[(long)(row0 - 3 + k) * CONV_DIM + c]) : 0.f;
  }
#pragma unroll
  for (int j = 0; j < CR; ++j) {
    float a = bias + xwin[j] * wv.x + xwin[j + 1] * wv.y + xwin[j + 2] * wv.z +
              xwin[j + 3] * wv.w;
    a = a / (1.f + expf(-a));
    int row = row0 + j;
    if (c < D_INNER)
      xp[(long)row * D_INNER + c] = f2bf(a);
    else
      bc[(long)row * (2 * D_STATE) + (c - D_INNER)] = f2bf(a);
  }
}

// ---------------------------------------------------------------- dt_pre: per (b,h,chunk)
__global__ __launch_bounds__(64) void dt_pre(const float* __restrict__ dtf,
                                             const float* __restrict__ dt_bias,
                                             const float* __restrict__ A_log,
                                             float* __restrict__ sgb,
                                             float* __restrict__ dsb,
                                             float* __restrict__ egb) {
  const int cc = blockIdx.x, hh = blockIdx.y, bb = blockIdx.z;
  const int l = threadIdx.x;
  const float Ah = -expf(A_log[hh]);
  const float dbias = dt_bias[hh];
  const long rowbase = (long)bb * SEQ + cc * TCH;
  float r0 = dtf[(rowbase + l) * NHEADS + hh] + dbias;
  float r1 = dtf[(rowbase + 64 + l) * NHEADS + hh] + dbias;
  float d0 = r0 > 20.f ? r0 : log1pf(expf(r0));
  float d1 = r1 > 20.f ? r1 : log1pf(expf(r1));
  float a0 = d0 * Ah, a1 = d1 * Ah;
#pragma unroll
  for (int d = 1; d < 64; d <<= 1) { float u = __shfl_up(a0, d); if (l >= d) a0 += u; }
#pragma unroll
  for (int d = 1; d < 64; d <<= 1) { float u = __shfl_up(a1, d); if (l >= d) a1 += u; }
  float t0 = __shfl(a0, 63);
  float s1 = a1 + t0;
  const long idx = ((long)(bb * 32 + hh) * 32 + cc) * 128;
  sgb[idx + l] = a0;       sgb[idx + 64 + l] = s1;
  dsb[idx + l] = d0;       dsb[idx + 64 + l] = d1;
  egb[idx + l] = dexp(a0); egb[idx + 64 + l] = dexp(s1);
}

// ---------------------------------------------------------------- ssd_g: per (b,chunk)
// (1) G = C.B^T stored PRE-SWIZZLED for ssd_y's linear gload.
// (2) B^T stored PRE-SWIZZLED (BTsw, layout == ssd_state's LDS BT) for linear gload.
__global__ __launch_bounds__(256, 2) void ssd_g_kernel(const u16* __restrict__ bcb,
                                                       u16* __restrict__ Gsw,
                                                       u16* __restrict__ BTsw) {
  const int cc = blockIdx.x, bb = blockIdx.y;
  const int tid = threadIdx.x, w = tid >> 6, l = tid & 63;
  __shared__ __align__(16) u16 BTl[128 * 128];
  const long rowbase = (long)bb * SEQ + cc * TCH;

  // transpose-stage B into LDS (swizzled scalar writes, proven pattern)
#pragma unroll
  for (int i = 0; i < 8; ++i) {
    int slot = i * 256 + tid, t = slot >> 4, nb = slot & 15;
    bf16x8 v = *(const bf16x8*)&bcb[(rowbase + t) * 256 + nb * 8];
    const u16* e = (const u16*)&v;
#pragma unroll
    for (int j = 0; j < 8; ++j) {
      int n = nb * 8 + j;
      BTl[n * 128 + (t ^ sw(n))] = e[j];
    }
  }
  // G = C.B^T (operands direct from global)
  bf16x8 cfr[2][4];
#pragma unroll
  for (int tt = 0; tt < 2; ++tt) {
    int t = (w * 2 + tt) * 16 + (l & 15);
#pragma unroll
    for (int kc = 0; kc < 4; ++kc)
      cfr[tt][kc] = *(const bf16x8*)&bcb[(rowbase + t) * 256 + 128 + kc * 32 +
                                         (l >> 4) * 8];
  }
  f32x4 g[2][8] = {};
#pragma unroll
  for (int st = 0; st < 8; ++st) {
    int s = st * 16 + (l & 15);
#pragma unroll
    for (int kc = 0; kc < 4; ++kc) {
      bf16x8 bfv = *(const bf16x8*)&bcb[(rowbase + s) * 256 + kc * 32 + (l >> 4) * 8];
      g[0][st] = __builtin_amdgcn_mfma_f32_16x16x32_bf16(cfr[0][kc], bfv, g[0][st], 0, 0, 0);
      g[1][st] = __builtin_amdgcn_mfma_f32_16x16x32_bf16(cfr[1][kc], bfv, g[1][st], 0, 0, 0);
    }
  }
  u16* Gb = Gsw + (long)(bb * 32 + cc) * 16384;
#pragma unroll
  for (int tt = 0; tt < 2; ++tt)
#pragma unroll
    for (int st = 0; st < 8; ++st)
#pragma unroll
      for (int r = 0; r < 4; ++r) {
        int t = (w * 2 + tt) * 16 + (l >> 4) * 4 + r;
        int s = st * 16 + (l & 15);
        int j = ((((s >> 3) ^ (t & 15)) << 3) | (s & 7));
        Gb[t * 128 + j] = f2bf(g[tt][st][r]);
      }
  __syncthreads();  // BTl complete
  // linear writeout of swizzled B^T
  u16* BTo = BTsw + (long)(bb * 32 + cc) * 16384;
#pragma unroll
  for (int i = 0; i < 8; ++i) {
    int idx = i * 256 + tid;
    *(bf16x8*)&BTo[idx * 8] = *(const bf16x8*)&BTl[idx * 8];
  }
}

// ---------------------------------------------------------------- SSD kernel A: chunk states
// B^T gloaded linearly from BTsw (pre-swizzled by ssd_g) — no per-head transpose.
__global__ __launch_bounds__(256, 3) void ssd_state_kernel(
    const u16* __restrict__ xp, const u16* __restrict__ BTsw,
    const float* __restrict__ dtf, const float* __restrict__ dt_bias,
    const float* __restrict__ A_log, u16* __restrict__ S,
    float* __restrict__ cdk) {
  const int hh = blockIdx.x, cc = blockIdx.y, bb = blockIdx.z;
  const int tid = threadIdx.x, w = tid >> 6, l = tid & 63;
  __shared__ __align__(16) u16 BT[128 * 128];   // B^T: [n][t ^ sw(n)]
  __shared__ __align__(16) u16 WXT[64 * 128];   // (w*x)^T: [p][t ^ sw(p)]
  __shared__ float ws[128];
  const long rowbase = (long)bb * SEQ + cc * TCH;
  const float Ah = -expf(A_log[hh]);
  const float dbias = dt_bias[hh];

  // gload pre-swizzled B^T (linear source & dest)
  const u16* BTg = BTsw + (long)(bb * 32 + cc) * 16384;
#pragma unroll
  for (int i = 0; i < 8; ++i) {
    int idx = i * 256 + tid;
    gload_lds16(BTg + idx * 8, (char*)BT + idx * 16);
  }
  if (w == 0) {  // cumulative decay sigma + weights
    float r0 = dtf[(rowbase + l) * NHEADS + hh] + dbias;
    float r1 = dtf[(rowbase + 64 + l) * NHEADS + hh] + dbias;
    float d0 = r0 > 20.f ? r0 : log1pf(expf(r0));
    float d1 = r1 > 20.f ? r1 : log1pf(expf(r1));
    float a0 = d0 * Ah, a1 = d1 * Ah;
#pragma unroll
    for (int d = 1; d < 64; d <<= 1) { float u = __shfl_up(a0, d); if (l >= d) a0 += u; }
#pragma unroll
    for (int d = 1; d < 64; d <<= 1) { float u = __shfl_up(a1, d); if (l >= d) a1 += u; }
    float t0 = __shfl(a0, 63);
    float tot = __shfl(a1, 63) + t0;
    ws[l] = dexp(tot - a0) * d0;
    ws[64 + l] = dexp(tot - (a1 + t0)) * d1;
    if (l == 0) cdk[(bb * 32 + hh) * NCHUNK + cc] = dexp(tot);
  }
  __syncthreads();  // ws ready
  // transpose-stage WXT = (w_t * x[t][p])^T
#pragma unroll
  for (int i = 0; i < 4; ++i) {
    int slot = i * 256 + tid, t = slot >> 3, pb = slot & 7;
    bf16x8 v = *(const bf16x8*)&xp[(rowbase + t) * D_INNER + hh * 64 + pb * 8];
    float wt = ws[t];
    const u16* e = (const u16*)&v;
#pragma unroll
    for (int j = 0; j < 8; ++j) {
      int p = pb * 8 + j;
      WXT[p * 128 + (t ^ sw(p))] = f2bf(bf2f(e[j]) * wt);
    }
  }
  __syncthreads();

  f32x4 acc[8] = {};
  const int p = w * 16 + (l & 15);
  const int swp = sw(p);
#pragma unroll
  for (int kc = 0; kc < 4; ++kc) {
    int tsl = kc * 32 + (l >> 4) * 8;
    bf16x8 af = *(const bf16x8*)&WXT[p * 128 + (tsl ^ swp)];
#pragma unroll
    for (int nt = 0; nt < 8; ++nt) {
      int n = nt * 16 + (l & 15);
      bf16x8 bfv = *(const bf16x8*)&BT[n * 128 + (tsl ^ sw(n))];
      acc[nt] = __builtin_amdgcn_mfma_f32_16x16x32_bf16(af, bfv, acc[nt], 0, 0, 0);
    }
  }
  u16* Sb = S + ((long)(bb * 32 + hh) * NCHUNK + cc) * 8192;
#pragma unroll
  for (int nt = 0; nt < 8; ++nt)
#pragma unroll
    for (int r = 0; r < 4; ++r) {
      int prow = w * 16 + (l >> 4) * 4 + r;
      Sb[prow * 128 + nt * 16 + (l & 15)] = f2bf(acc[nt][r]);
    }
}

// ---------------------------------------------------------------- SSD kernel B: inter-chunk combine
__global__ __launch_bounds__(256) void ssd_combine(u16* __restrict__ SH,
                                                   const float* __restrict__ cdk) {
  const int hh = blockIdx.y, bb = blockIdx.z;
  const int pp = blockIdx.x * 16 + (threadIdx.x >> 4);
  const int nn = (threadIdx.x & 15) * 8;
  const int bh = bb * 32 + hh;
  u16* base = SH + (long)bh * NCHUNK * 8192 + pp * 128 + nn;
  const float* ck = cdk + bh * NCHUNK;
  float h[8] = {};
  for (int c = 0; c < NCHUNK; ++c) {
    bf16x8 sv = *(bf16x8*)(base + (long)c * 8192);
    const u16* se = (const u16*)&sv;
    u16 o[8];
#pragma unroll
    for (int j = 0; j < 8; ++j) o[j] = f2bf(h[j]);
    *(bf16x8*)(base + (long)c * 8192) = *(bf16x8*)o;
    float d = ck[c];
#pragma unroll
    for (int j = 0; j < 8; ++j) h[j] = fmaf(h[j], d, bf2f(se[j]));
  }
}

// ---------------------------------------------------------------- SSD kernel C: Y + fused gating
// G gloaded linearly (pre-swizzled), masked in-place in LDS; Y1 = M@X, Y2 = C@H^T;
// yv re-staged into dead Gs (block-swizzled bf16) -> z gated at FULL-LINE granularity.
__global__ __launch_bounds__(256, 3) void ssd_y_kernel(
    const u16* __restrict__ xp, const u16* __restrict__ bcb,
    const u16* __restrict__ Gsw, const float* __restrict__ sgb,
    const float* __restrict__ dsb, const float* __restrict__ egb,
    const float* __restrict__ Dp, const u16* __restrict__ H,
    u16* __restrict__ zb, float* __restrict__ psum) {
  const int hh = blockIdx.x, cc = blockIdx.y, bb = blockIdx.z;
  const int tid = threadIdx.x, w = tid >> 6, l = tid & 63;
  __shared__ __align__(16) u16 Gs[128 * 128];   // G -> M (in-place) -> staged yv
  __shared__ __align__(16) u16 XT[64 * 128];    // x^T: [p][t ^ sw(p)]
  __shared__ float sig[128], dts[128], esg[128];
  const long rowbase = (long)bb * SEQ + cc * TCH;
  const float Dh = Dp[hh];

  // gload G (linear source & dest; ssd_g pre-swizzled the block layout)
  const u16* Gb = Gsw + (long)(bb * 32 + cc) * 16384;
#pragma unroll
  for (int i = 0; i < 8; ++i) {
    int idx = i * 256 + tid;
    gload_lds16(Gb + idx * 8, (char*)Gs + idx * 16);
  }
  // sigma/dt/exp(sigma) from dt_pre (coalesced)
  const long sidx = ((long)(bb * 32 + hh) * 32 + cc) * 128;
  if (tid < 128) {
    sig[tid] = sgb[sidx + tid];
    dts[tid] = dsb[sidx + tid];
    esg[tid] = egb[sidx + tid];
  }
  // transpose-stage XT (raw x), verified sw() swizzle
#pragma unroll
  for (int i = 0; i < 4; ++i) {
    int slot = i * 256 + tid, t = slot >> 3, pb = slot & 7;
    bf16x8 v = *(const bf16x8*)&xp[(rowbase + t) * D_INNER + hh * 64 + pb * 8];
    const u16* e = (const u16*)&v;
#pragma unroll
    for (int j = 0; j < 8; ++j) {
      int p = pb * 8 + j;
      XT[p * 128 + (t ^ sw(p))] = e[j];
    }
  }
  // C fragments direct from global (for Y2)
  bf16x8 cfr[2][4];
#pragma unroll
  for (int tt = 0; tt < 2; ++tt) {
    int t = (w * 2 + tt) * 16 + (l & 15);
#pragma unroll
    for (int kc = 0; kc < 4; ++kc)
      cfr[tt][kc] = *(const bf16x8*)&bcb[(rowbase + t) * 256 + 128 + kc * 32 +
                                         (l >> 4) * 8];
  }
  __syncthreads();  // G, XT, sig ready (barrier drains gload)

  // mask in place: thread owns row t = tid>>1, s-half = tid&1 (8 blocks of 8)
  {
    const int t = tid >> 1, half = tid & 1;
    const float sigt = sig[t];
#pragma unroll
    for (int wb = 0; wb < 8; ++wb) {
      int sblkL = half * 8 + wb;
      int sb2 = sblkL ^ (t & 15);
      bf16x8 v = *(const bf16x8*)&Gs[t * 128 + sb2 * 8];
      const u16* ge = (const u16*)&v;
      u16 o[8];
#pragma unroll
      for (int j = 0; j < 8; ++j) {
        int s = sblkL * 8 + j;
        float m = 0.f;
        if (s <= t) m = bf2f(ge[j]) * dexp(sigt - sig[s]) * dts[s];
        o[j] = f2bf(m);
      }
      *(bf16x8*)&Gs[t * 128 + sb2 * 8] = *(bf16x8*)o;
    }
  }
  __syncthreads();  // M ready

  // Y1 = M @ X
  f32x4 y1[2][4] = {};
#pragma unroll
  for (int kc = 0; kc < 4; ++kc) {
#pragma unroll
    for (int tt = 0; tt < 2; ++tt) {
      int t = (w * 2 + tt) * 16 + (l & 15);
      int want = kc * 4 + (l >> 4);
      int sb2 = want ^ (t & 15);
      bf16x8 mf = *(const bf16x8*)&Gs[t * 128 + sb2 * 8];
#pragma unroll
      for (int pt = 0; pt < 4; ++pt) {
        int p = pt * 16 + (l & 15);
        int ssl = kc * 32 + (l >> 4) * 8;
        bf16x8 xf = *(const bf16x8*)&XT[p * 128 + (ssl ^ sw(p))];
        y1[tt][pt] = __builtin_amdgcn_mfma_f32_16x16x32_bf16(mf, xf, y1[tt][pt], 0, 0, 0);
      }
    }
  }
  // Y2 = C @ H^T (H direct from global)
  f32x4 y2[2][4] = {};
  const u16* Hb = H + ((long)(bb * 32 + hh) * NCHUNK + cc) * 8192;
#pragma unroll
  for (int pt = 0; pt < 4; ++pt) {
    int p = pt * 16 + (l & 15);
#pragma unroll
    for (int kc = 0; kc < 4; ++kc) {
      bf16x8 hf = *(const bf16x8*)&Hb[p * 128 + kc * 32 + (l >> 4) * 8];
      y2[0][pt] = __builtin_amdgcn_mfma_f32_16x16x32_bf16(cfr[0][kc], hf, y2[0][pt], 0, 0, 0);
      y2[1][pt] = __builtin_amdgcn_mfma_f32_16x16x32_bf16(cfr[1][kc], hf, y2[1][pt], 0, 0, 0);
    }
  }
  // ---- stage yv (incl. D*x) into dead Gs, block-swizzled ----
  __syncthreads();  // all waves done reading Gs (Y1)
#pragma unroll
  for (int tt = 0; tt < 2; ++tt)
#pragma unroll
    for (int pt = 0; pt < 4; ++pt)
#pragma unroll
      for (int r = 0; r < 4; ++r) {
        int t = (w * 2 + tt) * 16 + (l >> 4) * 4 + r;
        int p = pt * 16 + (l & 15);
        float xv = bf2f(XT[p * 128 + (t ^ sw(p))]);
        float yv = y1[tt][pt][r] + esg[t] * y2[tt][pt][r] + Dh * xv;
        int blk = (p >> 3) ^ (t & 15);
        Gs[t * 128 + blk * 8 + (p & 7)] = f2bf(yv);
      }
  __syncthreads();  // yv staged
  // gate with silu(z): 2 threads per row, 32 consecutive channels each (full lines)
  {
    const int t = tid >> 1, half = tid & 1;
    const long off = (rowbase + t) * (long)D_INNER + hh * 64 + half * 32;
    float s2 = 0.f;
#pragma unroll
    for (int g2 = 0; g2 < 4; ++g2) {
      int pblk = half * 4 + g2;
      int lblk = pblk ^ (t & 15);
      bf16x8 yv8 = *(const bf16x8*)&Gs[t * 128 + lblk * 8];
      const u16* ye = (const u16*)&yv8;
      bf16x8 zv8 = *(const bf16x8*)&zb[off + g2 * 8];
      const u16* ze = (const u16*)&zv8;
      u16 o[8];
#pragma unroll
      for (int j = 0; j < 8; ++j) {
        float yv = bf2f(ye[j]);
        float zv = bf2f(ze[j]);
        float gg = yv * (zv / (1.f + expf(-zv)));
        o[j] = f2bf(gg);
        s2 += gg * gg;
      }
      *(bf16x8*)&zb[off + g2 * 8] = *(bf16x8*)o;
    }
    s2 += __shfl_xor(s2, 1);
    if (half == 0) psum[(rowbase + t) * NHEADS + hh] = s2;
  }
}

// ---------------------------------------------------------------- r_reduce: psum -> rvec
__global__ __launch_bounds__(256) void r_reduce(const float* __restrict__ psum,
                                                float* __restrict__ rvec) {
  int row = blockIdx.x * 256 + threadIdx.x;  // grid 32 -> 8192 rows
  const float4* p = (const float4*)&psum[(long)row * NHEADS];
  float s = 0.f;
#pragma unroll
  for (int i = 0; i < 8; ++i) {
    float4 v = p[i];
    s += v.x + v.y + v.z + v.w;
  }
  rvec[row] = rsqrtf(s * (1.f / D_INNER) + 1e-5f);
}

// ---------------------------------------------------------------- launch
extern "C" void kernel_launch(void* const* d_in, const int* in_sizes, int n_in,
                              void* d_out, int out_size, void* d_ws, size_t ws_size,
                              hipStream_t stream) {
  const float* x = (const float*)d_in[0];
  const float* ln_w = (const float*)d_in[1];
  const float* ln_b = (const float*)d_in[2];
  const float* in_proj_w = (const float*)d_in[3];
  const float* conv_w = (const float*)d_in[4];
  const float* conv_b = (const float*)d_in[5];
  const float* dt_bias = (const float*)d_in[6];
  const float* A_log = (const float*)d_in[7];
  const float* Dvec = (const float*)d_in[8];
  const float* norm_w = (const float*)d_in[9];
  const float* out_proj_w = (const float*)d_in[10];
  float* out = (float*)d_out;

  // workspace layout, max offset 120,627,200 < 123,478,016 (proven bound)
  char* ws = (char*)d_ws;
  u16* W2bf = (u16*)(ws + 0);                  //  4,194,304
  u16* zbf = (u16*)(ws + 4194304);             // 33,554,432 (z; ssd_y gates in-place)
  u16* xpart = (u16*)(ws + 37748736);          // 33,554,432
  u16* bcbf = (u16*)(ws + 71303168);           //  4,194,304 (B|C bf16 [8192][256])
  float* dtf = (float*)(ws + 75497472);        //  1,048,576
  float* cdk = (float*)(ws + 76546048);        //      8,192
  // region R: W1bf + xbcraw live until conv; afterwards SH/psum/Gsw/... reuse it
  u16* W1bf = (u16*)(ws + 76554240);           //  9,175,040
  u16* xbcraw = (u16*)(ws + 85729280);         // 37,748,736 (dead after conv)
  u16* SH = (u16*)(ws + 76554240);             // 33,554,432 -> ends 110,108,672 (after conv)
  float* psum = (float*)(ws + 110108672);      //  1,048,576 (after conv)
  float* rvec = (float*)(ws + 111157248);      //     32,768
  u16* Gsw = (u16*)(ws + 111190016);           //  2,097,152 (after conv)
  float* sgb = (float*)(ws + 113287168);       //  1,048,576 (after conv)
  float* dsb = (float*)(ws + 114335744);       //  1,048,576
  float* egb = (float*)(ws + 115384320);       //  1,048,576
  u16* BTsw = (u16*)(ws + 116432896);          //  4,194,304 -> ends 120,627,200 (after conv)
  u16* xnbf = (u16*)d_out;  // ln -> gemm1 scratch; gemm2 overwrites d_out last

  cvt_pad<<<512, 256, 0, stream>>>(in_proj_w, W1bf, D_IN_PROJ * D_MODEL,
                                   NPROJ_PAD * D_MODEL);
  cvt_w2s<<<512, 256, 0, stream>>>(out_proj_w, norm_w, W2bf, D_MODEL * D_INNER);
  ln_kernel<<<NROWS, 256, 0, stream>>>(x, ln_w, ln_b, xnbf);
  gemm_bt<<<35 * 64, 256, 0, stream>>>(xnbf, W1bf, D_MODEL, zbf, xbcraw, dtf);
  conv_silu_kernel<<<dim3(9, NROWS / CR), 256, 0, stream>>>(xbcraw, conv_w, conv_b,
                                                            xpart, bcbf);
  dt_pre<<<dim3(NCHUNK, NHEADS, 2), 64, 0, stream>>>(dtf, dt_bias, A_log, sgb, dsb,
                                                     egb);
  ssd_g_kernel<<<dim3(NCHUNK, 2), 256, 0, stream>>>(bcbf, Gsw, BTsw);
  ssd_state_kernel<<<dim3(32, NCHUNK, 2), 256, 0, stream>>>(xpart, BTsw, dtf, dt_bias,
                                                            A_log, SH, cdk);
  ssd_combine<<<dim3(4, 32, 2), 256, 0, stream>>>(SH, cdk);
  ssd_y_kernel<<<dim3(32, NCHUNK, 2), 256, 0, stream>>>(xpart, bcbf, Gsw, sgb, dsb,
                                                        egb, Dvec, SH, zbf, psum);
  r_reduce<<<32, 256, 0, stream>>>(psum, rvec);
  gemm2_kernel<<<1024, 256, 0, stream>>>(zbf, W2bf, out, x, rvec);
}

// Round 18
// 281.317 us; speedup vs baseline: 1.0169x; 1.0169x over previous
//
#include <hip/hip_runtime.h>
#include <cstdint>

#define D_MODEL 1024
#define D_INNER 2048
#define NHEADS 32
#define HEADDIM 64
#define D_STATE 128
#define CONV_DIM 2304
#define D_IN_PROJ 4384
#define SEQ 4096
#define NROWS 8192          // BATCH*SEQ
#define NPROJ_PAD 4480      // 35*128
#define TCH 128             // SSD chunk length
#define NCHUNK 32           // SEQ / TCH
#define CR 16               // conv rows per thread (4096 % 16 == 0)

typedef float f32x4 __attribute__((ext_vector_type(4)));
typedef __bf16 bf16x8 __attribute__((ext_vector_type(8)));
typedef unsigned short u16;

__device__ __forceinline__ u16 f2bf(float f) {
  uint32_t u = __builtin_bit_cast(uint32_t, f);
  u += 0x7FFFu + ((u >> 16) & 1u);
  return (u16)(u >> 16);
}
__device__ __forceinline__ float bf2f(u16 h) {
  return __builtin_bit_cast(float, (uint32_t)h << 16);
}
// decay exponent is mathematically <= 0; clamp kills rounding/edge inf risk
__device__ __forceinline__ float dexp(float a) { return expf(fminf(0.f, a)); }
// transpose-LDS t-swizzle (verified conflict-free both sides, round 9)
__device__ __forceinline__ int sw(int v) { return (((v & 7) ^ ((v >> 3) & 7)) << 3); }

typedef __attribute__((address_space(1))) const void gv_t;
typedef __attribute__((address_space(3))) void lv_t;
__device__ __forceinline__ void gload_lds16(const void* g, void* l) {
  __builtin_amdgcn_global_load_lds((gv_t*)g, (lv_t*)l, 16, 0, 0);
}

// ---------------------------------------------------------------- cvt f32->bf16 (+zero pad)
__global__ __launch_bounds__(256) void cvt_pad(const float* __restrict__ s,
                                               u16* __restrict__ d, int n_src, int n_dst) {
  int i = (blockIdx.x * 256 + threadIdx.x) * 4;
  int stride = gridDim.x * 256 * 4;
  for (; i < n_dst; i += stride) {
    ushort4 o;
    if (i < n_src) {
      float4 v = *(const float4*)&s[i];
      o.x = f2bf(v.x); o.y = f2bf(v.y); o.z = f2bf(v.z); o.w = f2bf(v.w);
    } else {
      o.x = o.y = o.z = o.w = 0;
    }
    *(ushort4*)&d[i] = o;
  }
}

// ---------------------------------------------------------------- cvt W2 with norm_w fold
__global__ __launch_bounds__(256) void cvt_w2s(const float* __restrict__ s,
                                               const float* __restrict__ nw,
                                               u16* __restrict__ d, int n) {
  int i = (blockIdx.x * 256 + threadIdx.x) * 4;
  int stride = gridDim.x * 256 * 4;
  for (; i < n; i += stride) {
    float4 v = *(const float4*)&s[i];
    int c = i & (D_INNER - 1);  // 4 consecutive cols, no wrap (i % 4 == 0)
    ushort4 o;
    o.x = f2bf(v.x * nw[c]);
    o.y = f2bf(v.y * nw[c + 1]);
    o.z = f2bf(v.z * nw[c + 2]);
    o.w = f2bf(v.w * nw[c + 3]);
    *(ushort4*)&d[i] = o;
  }
}

// ---------------------------------------------------------------- LayerNorm -> bf16
__global__ __launch_bounds__(256) void ln_kernel(const float* __restrict__ x,
                                                 const float* __restrict__ w,
                                                 const float* __restrict__ b,
                                                 u16* __restrict__ out) {
  int row = blockIdx.x, tid = threadIdx.x;
  const float4 v = *(const float4*)&x[(long)row * D_MODEL + tid * 4];
  float s1 = v.x + v.y + v.z + v.w;
  float s2 = v.x * v.x + v.y * v.y + v.z * v.z + v.w * v.w;
#pragma unroll
  for (int m = 32; m >= 1; m >>= 1) {
    s1 += __shfl_xor(s1, m);
    s2 += __shfl_xor(s2, m);
  }
  __shared__ float p1[4], p2[4];
  if ((tid & 63) == 0) { p1[tid >> 6] = s1; p2[tid >> 6] = s2; }
  __syncthreads();
  s1 = p1[0] + p1[1] + p1[2] + p1[3];
  s2 = p2[0] + p2[1] + p2[2] + p2[3];
  float mean = s1 * (1.f / D_MODEL);
  float var = s2 * (1.f / D_MODEL) - mean * mean;
  float rstd = rsqrtf(var + 1e-5f);
  const float4 wv = *(const float4*)&w[tid * 4];
  const float4 bv = *(const float4*)&b[tid * 4];
  ushort4 o;
  o.x = f2bf((v.x - mean) * rstd * wv.x + bv.x);
  o.y = f2bf((v.y - mean) * rstd * wv.y + bv.y);
  o.z = f2bf((v.z - mean) * rstd * wv.z + bv.z);
  o.w = f2bf((v.w - mean) * rstd * wv.w + bv.w);
  *(ushort4*)&out[(long)row * D_MODEL + tid * 4] = o;
}

// ---------------------------------------------------------------- bf16 GEMM C=A*B^T
// MODE 0: 2-D super-tiles of 8m x 5n per XCD (A 2MB + B 1.25MB fit XCD L2).
// MODE 1: XCD-exclusive m-slice (8 m-panels) x 8 n-panels as 4 super-tiles of
//   4m x 4n (A 2MB + B 2MB = 4MB L2). Epilogue: rvec row scale + residual.
template <int MODE>
__global__ __launch_bounds__(256, 4) void gemm_bt(const u16* __restrict__ A,
                                                  const u16* __restrict__ B, int K,
                                                  u16* __restrict__ zb,
                                                  u16* __restrict__ xb,
                                                  float* __restrict__ dtb,
                                                  float* __restrict__ C,
                                                  const float* __restrict__ resid,
                                                  const float* __restrict__ rvec) {
  __shared__ __align__(16) u16 As[128 * 64];  // 16 KB
  __shared__ __align__(16) u16 Bs[128 * 64];
  const int tid = threadIdx.x;
  int m0, n0;
  if (MODE == 0) {
    const int k = (blockIdx.x & 7) * 280 + (blockIdx.x >> 3);
    const int st = k / 40, inner = k % 40;
    m0 = ((st & 7) * 8 + (inner & 7)) * 128;
    n0 = ((st >> 3) * 5 + (inner >> 3)) * 128;
  } else {
    const int xcd = blockIdx.x & 7, i0 = blockIdx.x >> 3;  // i0 in [0,64)
    const int st = i0 >> 4, inner = i0 & 15;               // 4 super-tiles of 4m x 4n
    m0 = (xcd * 8 + (st & 1) * 4 + (inner & 3)) * 128;
    n0 = ((st >> 1) * 4 + (inner >> 2)) * 128;
  }
  const int w = tid >> 6, l = tid & 63;
  const int wm = w >> 1, wn = w & 1;

  f32x4 acc[4][4] = {};

  for (int k0 = 0; k0 < K; k0 += 64) {
#pragma unroll
    for (int i = 0; i < 4; ++i) {
      int idx = i * 256 + tid;                 // 1024 slots = 128 rows x 8 slots
      int row = idx >> 3, slot = idx & 7;
      int ks = slot ^ (row & 7);               // inverse swizzle on global source
      const u16* ga = A + (long)(m0 + row) * K + k0 + ks * 8;
      gload_lds16(ga, (char*)As + idx * 16);
      const u16* gb = B + (long)(n0 + row) * K + k0 + ks * 8;
      gload_lds16(gb, (char*)Bs + idx * 16);
    }
    __syncthreads();
    bf16x8 af[2][4], bfr[2][4];
#pragma unroll
    for (int kk = 0; kk < 2; ++kk)
#pragma unroll
      for (int f = 0; f < 4; ++f) {
        int rowa = wm * 64 + f * 16 + (l & 15);
        int ca = ((kk << 2) | (l >> 4)) ^ (rowa & 7);
        af[kk][f] = *(const bf16x8*)((const char*)As + rowa * 128 + ca * 16);
        int rowb = wn * 64 + f * 16 + (l & 15);
        int cb2 = ((kk << 2) | (l >> 4)) ^ (rowb & 7);
        bfr[kk][f] = *(const bf16x8*)((const char*)Bs + rowb * 128 + cb2 * 16);
      }
#pragma unroll
    for (int kk = 0; kk < 2; ++kk)
#pragma unroll
      for (int mf = 0; mf < 4; ++mf)
#pragma unroll
        for (int nf = 0; nf < 4; ++nf)
          acc[mf][nf] = __builtin_amdgcn_mfma_f32_16x16x32_bf16(
              af[kk][mf], bfr[kk][nf], acc[mf][nf], 0, 0, 0);
    __syncthreads();
  }
#pragma unroll
  for (int mf = 0; mf < 4; ++mf)
#pragma unroll
    for (int nf = 0; nf < 4; ++nf) {
      int col = n0 + wn * 64 + nf * 16 + (l & 15);
#pragma unroll
      for (int r = 0; r < 4; ++r) {
        int rowm = m0 + wm * 64 + mf * 16 + (l >> 4) * 4 + r;
        float v = acc[mf][nf][r];
        if (MODE == 0) {
          if (col < D_INNER)
            zb[(long)rowm * D_INNER + col] = f2bf(v);
          else if (col < D_INNER + CONV_DIM)
            xb[(long)rowm * CONV_DIM + (col - D_INNER)] = f2bf(v);
          else if (col < D_IN_PROJ)
            dtb[(long)rowm * NHEADS + (col - D_INNER - CONV_DIM)] = v;
        } else {
          long off = (long)rowm * D_MODEL + col;
          C[off] = v * rvec[rowm] + resid[off];
        }
      }
    }
}

// ---------------------------------------------------------------- conv1d + SiLU
// sliding window: 1 channel/thread, CR=16 rows/thread (19 loads -> 16 outputs).
__global__ __launch_bounds__(256) void conv_silu_kernel(const u16* __restrict__ xr,
                                                        const float* __restrict__ cw,
                                                        const float* __restrict__ cb,
                                                        u16* __restrict__ xp,
                                                        u16* __restrict__ bc) {
  const int c = blockIdx.x * 256 + threadIdx.x;   // 0..2303 exact (grid.x = 9)
  const int row0 = blockIdx.y * CR;
  const int t0 = row0 & (SEQ - 1);
  const float4 wv = *(const float4*)&cw[c * 4];
  const float bias = cb[c];
  float xwin[CR + 3];
#pragma unroll
  for (int k = 0; k < CR + 3; ++k) {
    int t = t0 - 3 + k;
    xwin[k] = (t >= 0) ? bf2f(xr[(long)(row0 - 3 + k) * CONV_DIM + c]) : 0.f;
  }
#pragma unroll
  for (int j = 0; j < CR; ++j) {
    float a = bias + xwin[j] * wv.x + xwin[j + 1] * wv.y + xwin[j + 2] * wv.z +
              xwin[j + 3] * wv.w;
    a = a / (1.f + expf(-a));
    int row = row0 + j;
    if (c < D_INNER)
      xp[(long)row * D_INNER + c] = f2bf(a);
    else
      bc[(long)row * (2 * D_STATE) + (c - D_INNER)] = f2bf(a);
  }
}

// ---------------------------------------------------------------- dt_pre: per (b,h,chunk)
__global__ __launch_bounds__(64) void dt_pre(const float* __restrict__ dtf,
                                             const float* __restrict__ dt_bias,
                                             const float* __restrict__ A_log,
                                             float* __restrict__ sgb,
                                             float* __restrict__ dsb,
                                             float* __restrict__ egb) {
  const int cc = blockIdx.x, hh = blockIdx.y, bb = blockIdx.z;
  const int l = threadIdx.x;
  const float Ah = -expf(A_log[hh]);
  const float dbias = dt_bias[hh];
  const long rowbase = (long)bb * SEQ + cc * TCH;
  float r0 = dtf[(rowbase + l) * NHEADS + hh] + dbias;
  float r1 = dtf[(rowbase + 64 + l) * NHEADS + hh] + dbias;
  float d0 = r0 > 20.f ? r0 : log1pf(expf(r0));
  float d1 = r1 > 20.f ? r1 : log1pf(expf(r1));
  float a0 = d0 * Ah, a1 = d1 * Ah;
#pragma unroll
  for (int d = 1; d < 64; d <<= 1) { float u = __shfl_up(a0, d); if (l >= d) a0 += u; }
#pragma unroll
  for (int d = 1; d < 64; d <<= 1) { float u = __shfl_up(a1, d); if (l >= d) a1 += u; }
  float t0 = __shfl(a0, 63);
  float s1 = a1 + t0;
  const long idx = ((long)(bb * 32 + hh) * 32 + cc) * 128;
  sgb[idx + l] = a0;       sgb[idx + 64 + l] = s1;
  dsb[idx + l] = d0;       dsb[idx + 64 + l] = d1;
  egb[idx + l] = dexp(a0); egb[idx + 64 + l] = dexp(s1);
}

// ---------------------------------------------------------------- ssd_g: per (b,chunk)
// (1) G = C.B^T stored PRE-SWIZZLED for ssd_y's linear gload.
// (2) B^T stored PRE-SWIZZLED (BTsw, layout == ssd_state's LDS BT) for linear gload.
__global__ __launch_bounds__(256, 2) void ssd_g_kernel(const u16* __restrict__ bcb,
                                                       u16* __restrict__ Gsw,
                                                       u16* __restrict__ BTsw) {
  const int cc = blockIdx.x, bb = blockIdx.y;
  const int tid = threadIdx.x, w = tid >> 6, l = tid & 63;
  __shared__ __align__(16) u16 BTl[128 * 128];
  const long rowbase = (long)bb * SEQ + cc * TCH;

  // transpose-stage B into LDS (swizzled scalar writes, proven pattern)
#pragma unroll
  for (int i = 0; i < 8; ++i) {
    int slot = i * 256 + tid, t = slot >> 4, nb = slot & 15;
    bf16x8 v = *(const bf16x8*)&bcb[(rowbase + t) * 256 + nb * 8];
    const u16* e = (const u16*)&v;
#pragma unroll
    for (int j = 0; j < 8; ++j) {
      int n = nb * 8 + j;
      BTl[n * 128 + (t ^ sw(n))] = e[j];
    }
  }
  // G = C.B^T (operands direct from global)
  bf16x8 cfr[2][4];
#pragma unroll
  for (int tt = 0; tt < 2; ++tt) {
    int t = (w * 2 + tt) * 16 + (l & 15);
#pragma unroll
    for (int kc = 0; kc < 4; ++kc)
      cfr[tt][kc] = *(const bf16x8*)&bcb[(rowbase + t) * 256 + 128 + kc * 32 +
                                         (l >> 4) * 8];
  }
  f32x4 g[2][8] = {};
#pragma unroll
  for (int st = 0; st < 8; ++st) {
    int s = st * 16 + (l & 15);
#pragma unroll
    for (int kc = 0; kc < 4; ++kc) {
      bf16x8 bfv = *(const bf16x8*)&bcb[(rowbase + s) * 256 + kc * 32 + (l >> 4) * 8];
      g[0][st] = __builtin_amdgcn_mfma_f32_16x16x32_bf16(cfr[0][kc], bfv, g[0][st], 0, 0, 0);
      g[1][st] = __builtin_amdgcn_mfma_f32_16x16x32_bf16(cfr[1][kc], bfv, g[1][st], 0, 0, 0);
    }
  }
  u16* Gb = Gsw + (long)(bb * 32 + cc) * 16384;
#pragma unroll
  for (int tt = 0; tt < 2; ++tt)
#pragma unroll
    for (int st = 0; st < 8; ++st)
#pragma unroll
      for (int r = 0; r < 4; ++r) {
        int t = (w * 2 + tt) * 16 + (l >> 4) * 4 + r;
        int s = st * 16 + (l & 15);
        int j = ((((s >> 3) ^ (t & 15)) << 3) | (s & 7));
        Gb[t * 128 + j] = f2bf(g[tt][st][r]);
      }
  __syncthreads();  // BTl complete
  // linear writeout of swizzled B^T
  u16* BTo = BTsw + (long)(bb * 32 + cc) * 16384;
#pragma unroll
  for (int i = 0; i < 8; ++i) {
    int idx = i * 256 + tid;
    *(bf16x8*)&BTo[idx * 8] = *(const bf16x8*)&BTl[idx * 8];
  }
}

// ---------------------------------------------------------------- SSD kernel A: chunk states
// B^T gloaded linearly from BTsw (pre-swizzled by ssd_g) — no per-head transpose.
__global__ __launch_bounds__(256, 3) void ssd_state_kernel(
    const u16* __restrict__ xp, const u16* __restrict__ BTsw,
    const float* __restrict__ dtf, const float* __restrict__ dt_bias,
    const float* __restrict__ A_log, u16* __restrict__ S,
    float* __restrict__ cdk) {
  const int hh = blockIdx.x, cc = blockIdx.y, bb = blockIdx.z;
  const int tid = threadIdx.x, w = tid >> 6, l = tid & 63;
  __shared__ __align__(16) u16 BT[128 * 128];   // B^T: [n][t ^ sw(n)]
  __shared__ __align__(16) u16 WXT[64 * 128];   // (w*x)^T: [p][t ^ sw(p)]
  __shared__ float ws[128];
  const long rowbase = (long)bb * SEQ + cc * TCH;
  const float Ah = -expf(A_log[hh]);
  const float dbias = dt_bias[hh];

  // gload pre-swizzled B^T (linear source & dest)
  const u16* BTg = BTsw + (long)(bb * 32 + cc) * 16384;
#pragma unroll
  for (int i = 0; i < 8; ++i) {
    int idx = i * 256 + tid;
    gload_lds16(BTg + idx * 8, (char*)BT + idx * 16);
  }
  if (w == 0) {  // cumulative decay sigma + weights
    float r0 = dtf[(rowbase + l) * NHEADS + hh] + dbias;
    float r1 = dtf[(rowbase + 64 + l) * NHEADS + hh] + dbias;
    float d0 = r0 > 20.f ? r0 : log1pf(expf(r0));
    float d1 = r1 > 20.f ? r1 : log1pf(expf(r1));
    float a0 = d0 * Ah, a1 = d1 * Ah;
#pragma unroll
    for (int d = 1; d < 64; d <<= 1) { float u = __shfl_up(a0, d); if (l >= d) a0 += u; }
#pragma unroll
    for (int d = 1; d < 64; d <<= 1) { float u = __shfl_up(a1, d); if (l >= d) a1 += u; }
    float t0 = __shfl(a0, 63);
    float tot = __shfl(a1, 63) + t0;
    ws[l] = dexp(tot - a0) * d0;
    ws[64 + l] = dexp(tot - (a1 + t0)) * d1;
    if (l == 0) cdk[(bb * 32 + hh) * NCHUNK + cc] = dexp(tot);
  }
  __syncthreads();  // ws ready
  // transpose-stage WXT = (w_t * x[t][p])^T
#pragma unroll
  for (int i = 0; i < 4; ++i) {
    int slot = i * 256 + tid, t = slot >> 3, pb = slot & 7;
    bf16x8 v = *(const bf16x8*)&xp[(rowbase + t) * D_INNER + hh * 64 + pb * 8];
    float wt = ws[t];
    const u16* e = (const u16*)&v;
#pragma unroll
    for (int j = 0; j < 8; ++j) {
      int p = pb * 8 + j;
      WXT[p * 128 + (t ^ sw(p))] = f2bf(bf2f(e[j]) * wt);
    }
  }
  __syncthreads();

  f32x4 acc[8] = {};
  const int p = w * 16 + (l & 15);
  const int swp = sw(p);
#pragma unroll
  for (int kc = 0; kc < 4; ++kc) {
    int tsl = kc * 32 + (l >> 4) * 8;
    bf16x8 af = *(const bf16x8*)&WXT[p * 128 + (tsl ^ swp)];
#pragma unroll
    for (int nt = 0; nt < 8; ++nt) {
      int n = nt * 16 + (l & 15);
      bf16x8 bfv = *(const bf16x8*)&BT[n * 128 + (tsl ^ sw(n))];
      acc[nt] = __builtin_amdgcn_mfma_f32_16x16x32_bf16(af, bfv, acc[nt], 0, 0, 0);
    }
  }
  u16* Sb = S + ((long)(bb * 32 + hh) * NCHUNK + cc) * 8192;
#pragma unroll
  for (int nt = 0; nt < 8; ++nt)
#pragma unroll
    for (int r = 0; r < 4; ++r) {
      int prow = w * 16 + (l >> 4) * 4 + r;
      Sb[prow * 128 + nt * 16 + (l & 15)] = f2bf(acc[nt][r]);
    }
}

// ---------------------------------------------------------------- SSD kernel B: inter-chunk combine
__global__ __launch_bounds__(256) void ssd_combine(u16* __restrict__ SH,
                                                   const float* __restrict__ cdk) {
  const int hh = blockIdx.y, bb = blockIdx.z;
  const int pp = blockIdx.x * 16 + (threadIdx.x >> 4);
  const int nn = (threadIdx.x & 15) * 8;
  const int bh = bb * 32 + hh;
  u16* base = SH + (long)bh * NCHUNK * 8192 + pp * 128 + nn;
  const float* ck = cdk + bh * NCHUNK;
  float h[8] = {};
  for (int c = 0; c < NCHUNK; ++c) {
    bf16x8 sv = *(bf16x8*)(base + (long)c * 8192);
    const u16* se = (const u16*)&sv;
    u16 o[8];
#pragma unroll
    for (int j = 0; j < 8; ++j) o[j] = f2bf(h[j]);
    *(bf16x8*)(base + (long)c * 8192) = *(bf16x8*)o;
    float d = ck[c];
#pragma unroll
    for (int j = 0; j < 8; ++j) h[j] = fmaf(h[j], d, bf2f(se[j]));
  }
}

// ---------------------------------------------------------------- SSD kernel C: Y + fused gating
// G gloaded linearly (pre-swizzled), masked in-place in LDS; Y1 = M@X, Y2 = C@H^T;
// yv re-staged into dead Gs (block-swizzled bf16) -> z gated at FULL-LINE granularity.
__global__ __launch_bounds__(256, 3) void ssd_y_kernel(
    const u16* __restrict__ xp, const u16* __restrict__ bcb,
    const u16* __restrict__ Gsw, const float* __restrict__ sgb,
    const float* __restrict__ dsb, const float* __restrict__ egb,
    const float* __restrict__ Dp, const u16* __restrict__ H,
    u16* __restrict__ zb, float* __restrict__ psum) {
  const int hh = blockIdx.x, cc = blockIdx.y, bb = blockIdx.z;
  const int tid = threadIdx.x, w = tid >> 6, l = tid & 63;
  __shared__ __align__(16) u16 Gs[128 * 128];   // G -> M (in-place) -> staged yv
  __shared__ __align__(16) u16 XT[64 * 128];    // x^T: [p][t ^ sw(p)]
  __shared__ float sig[128], dts[128], esg[128];
  const long rowbase = (long)bb * SEQ + cc * TCH;
  const float Dh = Dp[hh];

  // gload G (linear source & dest; ssd_g pre-swizzled the block layout)
  const u16* Gb = Gsw + (long)(bb * 32 + cc) * 16384;
#pragma unroll
  for (int i = 0; i < 8; ++i) {
    int idx = i * 256 + tid;
    gload_lds16(Gb + idx * 8, (char*)Gs + idx * 16);
  }
  // sigma/dt/exp(sigma) from dt_pre (coalesced)
  const long sidx = ((long)(bb * 32 + hh) * 32 + cc) * 128;
  if (tid < 128) {
    sig[tid] = sgb[sidx + tid];
    dts[tid] = dsb[sidx + tid];
    esg[tid] = egb[sidx + tid];
  }
  // transpose-stage XT (raw x), verified sw() swizzle
#pragma unroll
  for (int i = 0; i < 4; ++i) {
    int slot = i * 256 + tid, t = slot >> 3, pb = slot & 7;
    bf16x8 v = *(const bf16x8*)&xp[(rowbase + t) * D_INNER + hh * 64 + pb * 8];
    const u16* e = (const u16*)&v;
#pragma unroll
    for (int j = 0; j < 8; ++j) {
      int p = pb * 8 + j;
      XT[p * 128 + (t ^ sw(p))] = e[j];
    }
  }
  // C fragments direct from global (for Y2)
  bf16x8 cfr[2][4];
#pragma unroll
  for (int tt = 0; tt < 2; ++tt) {
    int t = (w * 2 + tt) * 16 + (l & 15);
#pragma unroll
    for (int kc = 0; kc < 4; ++kc)
      cfr[tt][kc] = *(const bf16x8*)&bcb[(rowbase + t) * 256 + 128 + kc * 32 +
                                         (l >> 4) * 8];
  }
  __syncthreads();  // G, XT, sig ready (barrier drains gload)

  // mask in place: thread owns row t = tid>>1, s-half = tid&1 (8 blocks of 8)
  {
    const int t = tid >> 1, half = tid & 1;
    const float sigt = sig[t];
#pragma unroll
    for (int wb = 0; wb < 8; ++wb) {
      int sblkL = half * 8 + wb;
      int sb2 = sblkL ^ (t & 15);
      bf16x8 v = *(const bf16x8*)&Gs[t * 128 + sb2 * 8];
      const u16* ge = (const u16*)&v;
      u16 o[8];
#pragma unroll
      for (int j = 0; j < 8; ++j) {
        int s = sblkL * 8 + j;
        float m = 0.f;
        if (s <= t) m = bf2f(ge[j]) * dexp(sigt - sig[s]) * dts[s];
        o[j] = f2bf(m);
      }
      *(bf16x8*)&Gs[t * 128 + sb2 * 8] = *(bf16x8*)o;
    }
  }
  __syncthreads();  // M ready

  // Y1 = M @ X
  f32x4 y1[2][4] = {};
#pragma unroll
  for (int kc = 0; kc < 4; ++kc) {
#pragma unroll
    for (int tt = 0; tt < 2; ++tt) {
      int t = (w * 2 + tt) * 16 + (l & 15);
      int want = kc * 4 + (l >> 4);
      int sb2 = want ^ (t & 15);
      bf16x8 mf = *(const bf16x8*)&Gs[t * 128 + sb2 * 8];
#pragma unroll
      for (int pt = 0; pt < 4; ++pt) {
        int p = pt * 16 + (l & 15);
        int ssl = kc * 32 + (l >> 4) * 8;
        bf16x8 xf = *(const bf16x8*)&XT[p * 128 + (ssl ^ sw(p))];
        y1[tt][pt] = __builtin_amdgcn_mfma_f32_16x16x32_bf16(mf, xf, y1[tt][pt], 0, 0, 0);
      }
    }
  }
  // Y2 = C @ H^T (H direct from global)
  f32x4 y2[2][4] = {};
  const u16* Hb = H + ((long)(bb * 32 + hh) * NCHUNK + cc) * 8192;
#pragma unroll
  for (int pt = 0; pt < 4; ++pt) {
    int p = pt * 16 + (l & 15);
#pragma unroll
    for (int kc = 0; kc < 4; ++kc) {
      bf16x8 hf = *(const bf16x8*)&Hb[p * 128 + kc * 32 + (l >> 4) * 8];
      y2[0][pt] = __builtin_amdgcn_mfma_f32_16x16x32_bf16(cfr[0][kc], hf, y2[0][pt], 0, 0, 0);
      y2[1][pt] = __builtin_amdgcn_mfma_f32_16x16x32_bf16(cfr[1][kc], hf, y2[1][pt], 0, 0, 0);
    }
  }
  // ---- stage yv (incl. D*x) into dead Gs, block-swizzled ----
  __syncthreads();  // all waves done reading Gs (Y1)
#pragma unroll
  for (int tt = 0; tt < 2; ++tt)
#pragma unroll
    for (int pt = 0; pt < 4; ++pt)
#pragma unroll
      for (int r = 0; r < 4; ++r) {
        int t = (w * 2 + tt) * 16 + (l >> 4) * 4 + r;
        int p = pt * 16 + (l & 15);
        float xv = bf2f(XT[p * 128 + (t ^ sw(p))]);
        float yv = y1[tt][pt][r] + esg[t] * y2[tt][pt][r] + Dh * xv;
        int blk = (p >> 3) ^ (t & 15);
        Gs[t * 128 + blk * 8 + (p & 7)] = f2bf(yv);
      }
  __syncthreads();  // yv staged
  // gate with silu(z): 2 threads per row, 32 consecutive channels each (full lines)
  {
    const int t = tid >> 1, half = tid & 1;
    const long off = (rowbase + t) * (long)D_INNER + hh * 64 + half * 32;
    float s2 = 0.f;
#pragma unroll
    for (int g2 = 0; g2 < 4; ++g2) {
      int pblk = half * 4 + g2;
      int lblk = pblk ^ (t & 15);
      bf16x8 yv8 = *(const bf16x8*)&Gs[t * 128 + lblk * 8];
      const u16* ye = (const u16*)&yv8;
      bf16x8 zv8 = *(const bf16x8*)&zb[off + g2 * 8];
      const u16* ze = (const u16*)&zv8;
      u16 o[8];
#pragma unroll
      for (int j = 0; j < 8; ++j) {
        float yv = bf2f(ye[j]);
        float zv = bf2f(ze[j]);
        float gg = yv * (zv / (1.f + expf(-zv)));
        o[j] = f2bf(gg);
        s2 += gg * gg;
      }
      *(bf16x8*)&zb[off + g2 * 8] = *(bf16x8*)o;
    }
    s2 += __shfl_xor(s2, 1);
    if (half == 0) psum[(rowbase + t) * NHEADS + hh] = s2;
  }
}

// ---------------------------------------------------------------- r_reduce: psum -> rvec
__global__ __launch_bounds__(256) void r_reduce(const float* __restrict__ psum,
                                                float* __restrict__ rvec) {
  int row = blockIdx.x * 256 + threadIdx.x;  // grid 32 -> 8192 rows
  const float4* p = (const float4*)&psum[(long)row * NHEADS];
  float s = 0.f;
#pragma unroll
  for (int i = 0; i < 8; ++i) {
    float4 v = p[i];
    s += v.x + v.y + v.z + v.w;
  }
  rvec[row] = rsqrtf(s * (1.f / D_INNER) + 1e-5f);
}

// ---------------------------------------------------------------- launch
extern "C" void kernel_launch(void* const* d_in, const int* in_sizes, int n_in,
                              void* d_out, int out_size, void* d_ws, size_t ws_size,
                              hipStream_t stream) {
  const float* x = (const float*)d_in[0];
  const float* ln_w = (const float*)d_in[1];
  const float* ln_b = (const float*)d_in[2];
  const float* in_proj_w = (const float*)d_in[3];
  const float* conv_w = (const float*)d_in[4];
  const float* conv_b = (const float*)d_in[5];
  const float* dt_bias = (const float*)d_in[6];
  const float* A_log = (const float*)d_in[7];
  const float* Dvec = (const float*)d_in[8];
  const float* norm_w = (const float*)d_in[9];
  const float* out_proj_w = (const float*)d_in[10];
  float* out = (float*)d_out;

  // workspace layout, max offset 120,627,200 < 123,478,016 (proven bound)
  char* ws = (char*)d_ws;
  u16* W2bf = (u16*)(ws + 0);                  //  4,194,304
  u16* zbf = (u16*)(ws + 4194304);             // 33,554,432 (z; ssd_y gates in-place)
  u16* xpart = (u16*)(ws + 37748736);          // 33,554,432
  u16* bcbf = (u16*)(ws + 71303168);           //  4,194,304 (B|C bf16 [8192][256])
  float* dtf = (float*)(ws + 75497472);        //  1,048,576
  float* cdk = (float*)(ws + 76546048);        //      8,192
  // region R: W1bf + xbcraw live until conv; afterwards SH/psum/Gsw/... reuse it
  u16* W1bf = (u16*)(ws + 76554240);           //  9,175,040
  u16* xbcraw = (u16*)(ws + 85729280);         // 37,748,736 (dead after conv)
  u16* SH = (u16*)(ws + 76554240);             // 33,554,432 -> ends 110,108,672 (after conv)
  float* psum = (float*)(ws + 110108672);      //  1,048,576 (after conv)
  float* rvec = (float*)(ws + 111157248);      //     32,768
  u16* Gsw = (u16*)(ws + 111190016);           //  2,097,152 (after conv)
  float* sgb = (float*)(ws + 113287168);       //  1,048,576 (after conv)
  float* dsb = (float*)(ws + 114335744);       //  1,048,576
  float* egb = (float*)(ws + 115384320);       //  1,048,576
  u16* BTsw = (u16*)(ws + 116432896);          //  4,194,304 -> ends 120,627,200 (after conv)
  u16* xnbf = (u16*)d_out;  // ln -> gemm1 scratch; gemm2 overwrites d_out last

  cvt_pad<<<512, 256, 0, stream>>>(in_proj_w, W1bf, D_IN_PROJ * D_MODEL,
                                   NPROJ_PAD * D_MODEL);
  cvt_w2s<<<512, 256, 0, stream>>>(out_proj_w, norm_w, W2bf, D_MODEL * D_INNER);
  ln_kernel<<<NROWS, 256, 0, stream>>>(x, ln_w, ln_b, xnbf);
  gemm_bt<0><<<35 * 64, 256, 0, stream>>>(xnbf, W1bf, D_MODEL, zbf, xbcraw, dtf,
                                          nullptr, nullptr, nullptr);
  conv_silu_kernel<<<dim3(9, NROWS / CR), 256, 0, stream>>>(xbcraw, conv_w, conv_b,
                                                            xpart, bcbf);
  dt_pre<<<dim3(NCHUNK, NHEADS, 2), 64, 0, stream>>>(dtf, dt_bias, A_log, sgb, dsb,
                                                     egb);
  ssd_g_kernel<<<dim3(NCHUNK, 2), 256, 0, stream>>>(bcbf, Gsw, BTsw);
  ssd_state_kernel<<<dim3(32, NCHUNK, 2), 256, 0, stream>>>(xpart, BTsw, dtf, dt_bias,
                                                            A_log, SH, cdk);
  ssd_combine<<<dim3(4, 32, 2), 256, 0, stream>>>(SH, cdk);
  ssd_y_kernel<<<dim3(32, NCHUNK, 2), 256, 0, stream>>>(xpart, bcbf, Gsw, sgb, dsb,
                                                        egb, Dvec, SH, zbf, psum);
  r_reduce<<<32, 256, 0, stream>>>(psum, rvec);
  gemm_bt<1><<<8 * 64, 256, 0, stream>>>(zbf, W2bf, D_INNER, nullptr, nullptr,
                                         nullptr, out, x, rvec);
}